// Round 13
// baseline (572.958 us; speedup 1.0000x reference)
//
#include <hip/hip_runtime.h>

// DMPNN ChemModel — round 13: r12 + NONTEMPORAL hints to protect the L2-
// resident mT plane (gather's hT rw stream + csr_src are single-use per
// plane-pass and were thrashing the 4MB XCD L2: 3.2 plane + 3.2 hT + 2 csr
// > 4MB). node_agg operands are all single-use -> nt. Gather batches 4->8
// wide (16 loads in flight). mfma O-store nt (consumed cross-XCD).
// Structural exploits (unchanged):
//  - m[src] only reads rows < N_NODES -> per-depth GEMM is [N,128]@[128,128]
//  - scatter only updates rows < N_NODES -> store h[0:N]; rows >= N
//    recomputed from packed z (bf16) in node aggregation.
// depth hardcoded to 3.

#define NN 100000
#define NE 500000
#define HID 128
#define NG 2048
#define NB_SCAN 391    // ceil(NN/256)
#define NBLK256 391    // ceil(NN/256): per-plane blocks (256 nodes/block)

typedef __attribute__((ext_vector_type(8))) short bf16x8;
typedef __attribute__((ext_vector_type(4))) float f32x4;

__device__ __forceinline__ float b2f(ushort u) {
  return __uint_as_float(((uint)u) << 16);
}
__device__ __forceinline__ ushort f2b(float f) {
  uint u = __float_as_uint(f);
  return (ushort)((u + 0x7FFF + ((u >> 16) & 1)) >> 16);
}
__device__ __forceinline__ void acc8(float* a, bf16x8 v) {
#pragma unroll
  for (int j = 0; j < 8; ++j) a[j] += b2f((ushort)v[j]);
}
__device__ __forceinline__ bf16x8 pack8(const float* a) {
  bf16x8 o;
#pragma unroll
  for (int j = 0; j < 8; ++j) o[j] = (short)f2b(a[j]);
  return o;
}
// tiled address of the 16B chunk at (row n, col c8), c8 multiple of 8
__device__ __forceinline__ size_t taddr(int n, int c8) {
  return ((size_t)(c8 >> 4) * NN + n) * 16 + (c8 & 8);
}

// ------- K1: hT[e] = relu(W_i @ [x[src[e]], ea[e]]), 8 cols/thread ----------
__global__ __launch_bounds__(256) void k_init_h8(const int* __restrict__ src,
    const float* __restrict__ x, const float* __restrict__ ea,
    const float* __restrict__ Wi, ushort* __restrict__ hT) {
  __shared__ float wis[HID * 7];
  for (int i = threadIdx.x; i < HID * 7; i += 256) wis[i] = Wi[i];
  __syncthreads();
  int idx = blockIdx.x * 256 + threadIdx.x;
  int e = idx >> 4, chunk = idx & 15;
  if (e >= NN) return;
  int s = src[e];
  float4 xv = *reinterpret_cast<const float4*>(&x[(size_t)s * 4]);
  float e0 = ea[(size_t)e*3+0], e1 = ea[(size_t)e*3+1], e2 = ea[(size_t)e*3+2];
  const float* w = &wis[chunk * 56];
  float a[8];
#pragma unroll
  for (int j = 0; j < 8; ++j) {
    const float* wj = &w[j * 7];
    float t = xv.x*wj[0] + xv.y*wj[1] + xv.z*wj[2] + xv.w*wj[3]
            + e0*wj[4] + e1*wj[5] + e2*wj[6];
    a[j] = fmaxf(t, 0.f);
  }
  *reinterpret_cast<bf16x8*>(&hT[((size_t)(chunk >> 1) * NN + e) * 16 + (chunk & 1) * 8]) = pack8(a);
}

// ---------------- CSR build over dst ----------------------------------------
__global__ __launch_bounds__(256) void k_hist(const int* __restrict__ dst,
    int* __restrict__ cnt) {
  int e = blockIdx.x * 256 + threadIdx.x;
  if (e < NE) atomicAdd(&cnt[dst[e]], 1);
}

__global__ __launch_bounds__(256) void k_scan1(const int* __restrict__ cnt,
    int* __restrict__ outp, int* __restrict__ bsums) {
  __shared__ int s[256];
  int t = threadIdx.x;
  int i = blockIdx.x * 256 + t;
  int v = (i < NN) ? cnt[i] : 0;
  s[t] = v;
  __syncthreads();
  for (int off = 1; off < 256; off <<= 1) {
    int u = (t >= off) ? s[t - off] : 0;
    __syncthreads();
    s[t] += u;
    __syncthreads();
  }
  if (i < NN) outp[i] = s[t] - v;
  if (t == 255) bsums[blockIdx.x] = s[255];
}

__global__ __launch_bounds__(512) void k_scan2(int* __restrict__ bsums) {
  __shared__ int s[512];
  int t = threadIdx.x;
  int v = (t < NB_SCAN) ? bsums[t] : 0;
  s[t] = v;
  __syncthreads();
  for (int off = 1; off < 512; off <<= 1) {
    int u = (t >= off) ? s[t - off] : 0;
    __syncthreads();
    s[t] += u;
    __syncthreads();
  }
  if (t < NB_SCAN) bsums[t] = s[t] - v;
}

__global__ __launch_bounds__(256) void k_scan3(int* __restrict__ outp,
    const int* __restrict__ bsums) {
  int i = blockIdx.x * 256 + threadIdx.x;
  if (i < NN) outp[i] += bsums[blockIdx.x];
  if (i == 0) outp[NN] = NE;
}

// fill CSR: lo edges (e<NN) fill UP from rowptr[d] (csr_eid recorded);
// hi edges fill DOWN from rowptr[d+1]-1 with packed z. After this kernel,
// cur_lo[d] == lo-count of d (node_agg uses mid = rowptr[d] + cur_lo[d]).
__global__ __launch_bounds__(256) void k_fill2z(const int* __restrict__ src,
    const int* __restrict__ dst, const int* __restrict__ rowptr,
    int* __restrict__ cur_lo, int* __restrict__ cur_hi,
    int* __restrict__ csr_src, int* __restrict__ csr_eid,
    const float* __restrict__ x, const float* __restrict__ ea,
    ushort* __restrict__ zpk) {
  int e = blockIdx.x * 256 + threadIdx.x;
  if (e >= NE) return;
  int d = dst[e];
  int s = src[e];
  int o;
  if (e < NN) {
    o = rowptr[d] + atomicAdd(&cur_lo[d], 1);
    csr_eid[o] = e;
  } else {
    o = rowptr[d + 1] - 1 - atomicAdd(&cur_hi[d], 1);
    float4 xv = *reinterpret_cast<const float4*>(&x[(size_t)s * 4]);
    bf16x8 z;
    z[0] = (short)f2b(xv.x); z[1] = (short)f2b(xv.y);
    z[2] = (short)f2b(xv.z); z[3] = (short)f2b(xv.w);
    z[4] = (short)f2b(ea[(size_t)e*3+0]);
    z[5] = (short)f2b(ea[(size_t)e*3+1]);
    z[6] = (short)f2b(ea[(size_t)e*3+2]);
    z[7] = 0;
    *reinterpret_cast<bf16x8*>(&zpk[(size_t)o * 8]) = z;
  }
  csr_src[o] = s;
}

// weight convert (blocks 0..63) + graph offsets (blocks 64..72), fused
__global__ __launch_bounds__(256) void k_misc(const float* __restrict__ Wm,
    const float* __restrict__ Wa, ushort* __restrict__ wmb,
    ushort* __restrict__ wab, const int* __restrict__ batch,
    int* __restrict__ goff) {
  int gb = blockIdx.x;
  if (gb < 64) {
    int i = gb * 256 + threadIdx.x;
    wmb[i] = f2b(Wm[i]);
    int c = i >> 7, k = i & 127;
    wab[i] = f2b(Wa[c * 132 + 4 + k]);
  } else {
    int g = (gb - 64) * 256 + threadIdx.x;
    if (g > NG) return;
    int lo = 0, hi = NN;
    while (lo < hi) { int mid = (lo + hi) >> 1; if (batch[mid] < g) lo = mid + 1; else hi = mid; }
    goff[g] = lo;
  }
}

// ---- MFMA GEMM (2x2 waves, tiled A/O): O = relu(A@Wb.T [+x-part]) ----------
template <bool HASX>
__global__ __launch_bounds__(256) void k_mfma(const ushort* __restrict__ A,
    const ushort* __restrict__ Wb, const float* __restrict__ X,
    const float* __restrict__ WaF, ushort* __restrict__ O, int nrows) {
  int tid = threadIdx.x;
  int wave = tid >> 6;
  int lane = tid & 63;
  int wr = wave >> 1, wc = wave & 1;
  int row0 = blockIdx.x * 64 + wr * 32;
  int col0 = wc * 64;
  int l15 = lane & 15, l4 = lane >> 4;

  f32x4 acc[2][4];
#pragma unroll
  for (int mi = 0; mi < 2; ++mi)
#pragma unroll
    for (int ni = 0; ni < 4; ++ni) acc[mi][ni] = (f32x4){0.f, 0.f, 0.f, 0.f};

  if (HASX) {
    float4 wv[4];
#pragma unroll
    for (int ni = 0; ni < 4; ++ni)
      wv[ni] = *reinterpret_cast<const float4*>(&WaF[(size_t)(col0 + ni * 16 + l15) * 132]);
#pragma unroll
    for (int mi = 0; mi < 2; ++mi)
#pragma unroll
      for (int j = 0; j < 4; ++j) {
        int r = row0 + mi * 16 + l4 * 4 + j;
        if (r < nrows) {
          float4 xv = *reinterpret_cast<const float4*>(&X[(size_t)r * 4]);
#pragma unroll
          for (int ni = 0; ni < 4; ++ni)
            acc[mi][ni][j] = xv.x * wv[ni].x + xv.y * wv[ni].y
                           + xv.z * wv[ni].z + xv.w * wv[ni].w;
        }
      }
  }

  const bf16x8 zero8 = {0, 0, 0, 0, 0, 0, 0, 0};
#pragma unroll
  for (int k0 = 0; k0 < HID; k0 += 32) {
    bf16x8 a[2], b[4];
    int c8 = k0 + l4 * 8;
#pragma unroll
    for (int mi = 0; mi < 2; ++mi) {
      int r = row0 + mi * 16 + l15;
      a[mi] = (r < nrows)
            ? *reinterpret_cast<const bf16x8*>(&A[taddr(r, c8)])
            : zero8;
    }
#pragma unroll
    for (int ni = 0; ni < 4; ++ni) {
      int c = col0 + ni * 16 + l15;
      b[ni] = *reinterpret_cast<const bf16x8*>(&Wb[(size_t)c * HID + k0 + l4 * 8]);
    }
#pragma unroll
    for (int mi = 0; mi < 2; ++mi)
#pragma unroll
      for (int ni = 0; ni < 4; ++ni)
        acc[mi][ni] = __builtin_amdgcn_mfma_f32_16x16x32_bf16(a[mi], b[ni], acc[mi][ni], 0, 0, 0);
  }

#pragma unroll
  for (int mi = 0; mi < 2; ++mi)
#pragma unroll
    for (int j = 0; j < 4; ++j) {
      int r = row0 + mi * 16 + l4 * 4 + j;
      if (r >= nrows) continue;
#pragma unroll
      for (int ni = 0; ni < 4; ++ni) {
        int plane = wc * 4 + ni;  // (col0 + ni*16) >> 4
        ushort v = f2b(fmaxf(acc[mi][ni][j], 0.f));
        __builtin_nontemporal_store(v, &O[((size_t)plane * NN + r) * 16 + l15]);
      }
    }
}

// ----- K3: XCD-pinned plane gather; 1 thread/(node,plane) owns 32B ----------
// plane = bid & 7 (round-robin dispatch pins plane p to XCD p; 3.2MB mT plane
// L2-resident). hT rw + csr_src are single-use per plane-pass -> NONTEMPORAL
// (keeps mT + rowptr resident: 3.6MB < 4MB L2). 8-wide exact-predicated
// batches x 2 halves = 16 loads in flight.
__global__ __launch_bounds__(256) void k_gather_x(const ushort* __restrict__ mT,
    const int* __restrict__ rowptr, const int* __restrict__ csr_src,
    ushort* __restrict__ hT) {
  int plane = blockIdx.x & 7;
  int nb = blockIdx.x >> 3;
  int n = nb * 256 + threadIdx.x;
  if (n >= NN) return;
  size_t pb = (size_t)plane * NN;
  size_t base = (pb + n) * 16;
  const bf16x8 zero8 = {0, 0, 0, 0, 0, 0, 0, 0};
  float a[16];
  bf16x8 h0 = __builtin_nontemporal_load(reinterpret_cast<const bf16x8*>(&hT[base]));
  bf16x8 h1 = __builtin_nontemporal_load(reinterpret_cast<const bf16x8*>(&hT[base + 8]));
#pragma unroll
  for (int j = 0; j < 8; ++j) { a[j] = b2f((ushort)h0[j]); a[8+j] = b2f((ushort)h1[j]); }
  int beg = rowptr[n], end = rowptr[n + 1];
  for (int i = beg; i < end; i += 8) {
    bf16x8 v0[8], v1[8];
#pragma unroll
    for (int k = 0; k < 8; ++k) {
      v0[k] = zero8; v1[k] = zero8;
      if (i + k < end) {
        int s = __builtin_nontemporal_load(&csr_src[i + k]);
        size_t sb = (pb + s) * 16;
        v0[k] = *reinterpret_cast<const bf16x8*>(&mT[sb]);
        v1[k] = *reinterpret_cast<const bf16x8*>(&mT[sb + 8]);
      }
    }
#pragma unroll
    for (int k = 0; k < 8; ++k) { acc8(a, v0[k]); acc8(a + 8, v1[k]); }
  }
  __builtin_nontemporal_store(pack8(a), reinterpret_cast<bf16x8*>(&hT[base]));
  __builtin_nontemporal_store(pack8(a + 8), reinterpret_cast<bf16x8*>(&hT[base + 8]));
}

// ------ K4: node-major node_agg (16 t/node): zpk read ONCE ------------------
// All operands single-use -> nontemporal. mid = rowptr[n] + locnt[n].
__global__ __launch_bounds__(256) void k_node_agg3(const ushort* __restrict__ hT,
    const int* __restrict__ rowptr, const int* __restrict__ locnt,
    const int* __restrict__ csr_eid, const ushort* __restrict__ zpk,
    const float* __restrict__ Wi, ushort* __restrict__ neT) {
  int idx = blockIdx.x * 256 + threadIdx.x;
  int n = idx >> 4;
  int t = idx & 15;
  int plane = t >> 1;
  int half8 = (t & 1) * 8;
  int c8 = t * 8;
  float w[8][7];
#pragma unroll
  for (int j = 0; j < 8; ++j)
#pragma unroll
    for (int k = 0; k < 7; ++k) w[j][k] = Wi[(c8 + j) * 7 + k];
  if (n >= NN) return;
  size_t pb = (size_t)plane * NN;
  int beg = rowptr[n], end = rowptr[n + 1];
  int mid = beg + locnt[n];
  const bf16x8 zero8 = {0, 0, 0, 0, 0, 0, 0, 0};
  float a[8];
#pragma unroll
  for (int j = 0; j < 8; ++j) a[j] = 0.f;

  // lo: e < NN -> hT rows (each read exactly once), exact predicated 4-batches
  for (int i = beg; i < mid; i += 4) {
    bf16x8 v[4];
#pragma unroll
    for (int k = 0; k < 4; ++k) {
      v[k] = zero8;
      if (i + k < mid) {
        int e = csr_eid[i + k];
        v[k] = __builtin_nontemporal_load(
            reinterpret_cast<const bf16x8*>(&hT[(pb + e) * 16 + half8]));
      }
    }
#pragma unroll
    for (int k = 0; k < 4; ++k) acc8(a, v[k]);
  }

  // hi: packed z, 16 lanes of a node share each 16B read (1 request)
  for (int i = mid; i < end; i += 4) {
    bf16x8 zv[4];
#pragma unroll
    for (int k = 0; k < 4; ++k) {
      zv[k] = zero8;
      if (i + k < end)
        zv[k] = __builtin_nontemporal_load(
            reinterpret_cast<const bf16x8*>(&zpk[(size_t)(i + k) * 8]));
    }
#pragma unroll
    for (int k = 0; k < 4; ++k) {
      if (i + k < end) {
        float z0 = b2f((ushort)zv[k][0]), z1 = b2f((ushort)zv[k][1]);
        float z2 = b2f((ushort)zv[k][2]), z3 = b2f((ushort)zv[k][3]);
        float z4 = b2f((ushort)zv[k][4]), z5 = b2f((ushort)zv[k][5]);
        float z6 = b2f((ushort)zv[k][6]);
#pragma unroll
        for (int j = 0; j < 8; ++j) {
          float tt = z0*w[j][0] + z1*w[j][1] + z2*w[j][2] + z3*w[j][3]
                   + z4*w[j][4] + z5*w[j][5] + z6*w[j][6];
          a[j] += fmaxf(tt, 0.f);
        }
      }
    }
  }
  __builtin_nontemporal_store(pack8(a),
      reinterpret_cast<bf16x8*>(&neT[(pb + n) * 16 + half8]));
}

// ---------------- K6: g[gid] = sum of tiled node_act rows (fp32 out) --------
__global__ __launch_bounds__(256) void k_pool(const ushort* __restrict__ na,
    const int* __restrict__ goff, float* __restrict__ g) {
  int idx = blockIdx.x * 256 + threadIdx.x;
  int gid = idx >> 4;
  if (gid >= NG) return;
  int c8 = (idx & 15) * 8;
  size_t pbase = (size_t)(c8 >> 4) * NN;
  int off = c8 & 8;
  int beg = goff[gid], end = goff[gid + 1];
  float a[8];
#pragma unroll
  for (int j = 0; j < 8; ++j) a[j] = 0.f;
  for (int n = beg; n < end; ++n)
    acc8(a, *reinterpret_cast<const bf16x8*>(&na[(pbase + n) * 16 + off]));
  *reinterpret_cast<float4*>(&g[(size_t)gid * HID + c8]) = make_float4(a[0], a[1], a[2], a[3]);
  *reinterpret_cast<float4*>(&g[(size_t)gid * HID + c8 + 4]) = make_float4(a[4], a[5], a[6], a[7]);
}

// ---------------- FFN fp32 GEMM + final dot ---------------------------------
template <bool RELU>
__global__ __launch_bounds__(256) void k_gemm64(const float* __restrict__ A,
    const float* __restrict__ W, const float* __restrict__ bias,
    float* __restrict__ O, int nrows, int K, int N) {
  __shared__ float As[64][33];
  __shared__ float Bs[32][68];
  int tid = threadIdx.x;
  int row0 = blockIdx.x * 64;
  int col0 = blockIdx.y * 64;
  int tn = tid & 15;
  int tm = tid >> 4;
  float acc[4][4];
#pragma unroll
  for (int i = 0; i < 4; ++i)
#pragma unroll
    for (int j = 0; j < 4; ++j) acc[i][j] = 0.f;

  for (int k0 = 0; k0 < K; k0 += 32) {
    int ar = tid >> 3;
    int ak = (tid & 7) << 2;
#pragma unroll
    for (int rr = 0; rr < 2; ++rr) {
      int r = row0 + ar + rr * 32;
      float4 v = make_float4(0.f, 0.f, 0.f, 0.f);
      if (r < nrows) v = *reinterpret_cast<const float4*>(&A[(size_t)r * K + k0 + ak]);
      As[ar + rr*32][ak+0] = v.x; As[ar + rr*32][ak+1] = v.y;
      As[ar + rr*32][ak+2] = v.z; As[ar + rr*32][ak+3] = v.w;
    }
    int c = tid & 63;
    int kq = tid >> 6;
#pragma unroll
    for (int it = 0; it < 2; ++it) {
      int kk = kq * 4 + it * 16;
      float4 v = *reinterpret_cast<const float4*>(&W[(size_t)(col0 + c) * K + k0 + kk]);
      Bs[kk+0][c] = v.x; Bs[kk+1][c] = v.y; Bs[kk+2][c] = v.z; Bs[kk+3][c] = v.w;
    }
    __syncthreads();
#pragma unroll 8
    for (int k = 0; k < 32; ++k) {
      float av[4];
#pragma unroll
      for (int i = 0; i < 4; ++i) av[i] = As[tm*4 + i][k];
      float4 bv = *reinterpret_cast<const float4*>(&Bs[k][tn*4]);
#pragma unroll
      for (int i = 0; i < 4; ++i) {
        acc[i][0] = fmaf(av[i], bv.x, acc[i][0]);
        acc[i][1] = fmaf(av[i], bv.y, acc[i][1]);
        acc[i][2] = fmaf(av[i], bv.z, acc[i][2]);
        acc[i][3] = fmaf(av[i], bv.w, acc[i][3]);
      }
    }
    __syncthreads();
  }
#pragma unroll
  for (int i = 0; i < 4; ++i) {
    int r = row0 + tm * 4 + i;
    if (r >= nrows) continue;
    float4 o;
    int c = col0 + tn * 4;
    o.x = acc[i][0] + bias[c+0];
    o.y = acc[i][1] + bias[c+1];
    o.z = acc[i][2] + bias[c+2];
    o.w = acc[i][3] + bias[c+3];
    if (RELU) {
      o.x = fmaxf(o.x, 0.f); o.y = fmaxf(o.y, 0.f);
      o.z = fmaxf(o.z, 0.f); o.w = fmaxf(o.w, 0.f);
    }
    *reinterpret_cast<float4*>(&O[(size_t)r * N + c]) = o;
  }
}

__global__ __launch_bounds__(256) void k_last(const float* __restrict__ g3,
    const float* __restrict__ Wl, const float* __restrict__ bl,
    float* __restrict__ out) {
  int wid = (blockIdx.x * 256 + threadIdx.x) >> 6;
  int lane = threadIdx.x & 63;
  if (wid >= NG) return;
  float a = g3[(size_t)wid*128 + lane] * Wl[lane]
          + g3[(size_t)wid*128 + 64 + lane] * Wl[64 + lane];
  for (int off = 32; off; off >>= 1) a += __shfl_down(a, off);
  if (lane == 0) out[wid] = a + bl[0];
}

extern "C" void kernel_launch(void* const* d_in, const int* in_sizes, int n_in,
                              void* d_out, int out_size, void* d_ws, size_t ws_size,
                              hipStream_t stream) {
  const float* x    = (const float*)d_in[0];
  const int*   eidx = (const int*)d_in[1];
  const float* ea   = (const float*)d_in[2];
  const int*   batch= (const int*)d_in[3];
  const float* Wi   = (const float*)d_in[5];
  const float* Wm   = (const float*)d_in[6];
  const float* Wa   = (const float*)d_in[7];
  const float* W1   = (const float*)d_in[8];
  const float* b1   = (const float*)d_in[9];
  const float* W2   = (const float*)d_in[10];
  const float* b2   = (const float*)d_in[11];
  const float* Wl   = (const float*)d_in[12];
  const float* bl   = (const float*)d_in[13];
  float* out = (float*)d_out;

  const int* src = eidx;
  const int* dst = eidx + NE;

  // ---- workspace layout ----
  char* p = (char*)d_ws;
  ushort* hb  = (ushort*)p; p += (size_t)NN * HID * 2;   // 25.6 MB (tiled [8][NN][16])
  ushort* mb  = (ushort*)p; p += (size_t)NN * HID * 2;   // 25.6 MB (tiled)
  ushort* wmb = (ushort*)p; p += (size_t)HID * HID * 2;  // 32 KB
  ushort* wab = (ushort*)p; p += (size_t)HID * HID * 2;  // 32 KB
  ushort* zpk = (ushort*)p; p += (size_t)NE * 8 * 2;     // 8 MB (bf16x8 per CSR slot)
  float* g  = (float*)p; p += (size_t)NG * 128 * 4;      // 1 MB
  float* g2 = (float*)p; p += (size_t)NG * 512 * 4;      // 4 MB
  float* g3 = (float*)p; p += (size_t)NG * 128 * 4;      // 1 MB
  int* csr_src = (int*)p; p += (size_t)NE * 4;           // 2 MB
  int* csr_eid = (int*)p; p += (size_t)NE * 4;           // 2 MB
  // zeroed region: cnt | cur_lo | cur_hi  (3*NN ints)
  int* cnt    = (int*)p; p += (size_t)NN * 4;
  int* cur_lo = (int*)p; p += (size_t)NN * 4;
  int* cur_hi = (int*)p; p += (size_t)NN * 4;
  // un-zeroed
  int* rowptr = (int*)p; p += (size_t)(NN + 4) * 4;
  int* bsums  = (int*)p; p += 512 * 4;
  int* goff   = (int*)p; p += (size_t)(NG + 4) * 4;

  // ---- CSR over dst (lo up-fill / hi down-fill) + hi-z + goff ----
  hipMemsetAsync(cnt, 0, (size_t)3 * NN * sizeof(int), stream);
  k_hist <<<(NE + 255) / 256, 256, 0, stream>>>(dst, cnt);
  k_scan1<<<NB_SCAN, 256, 0, stream>>>(cnt, rowptr, bsums);
  k_scan2<<<1, 512, 0, stream>>>(bsums);
  k_scan3<<<NB_SCAN, 256, 0, stream>>>(rowptr, bsums);
  k_fill2z<<<(NE + 255) / 256, 256, 0, stream>>>(src, dst, rowptr,
                                                 cur_lo, cur_hi, csr_src, csr_eid,
                                                 x, ea, zpk);
  k_misc<<<64 + 9, 256, 0, stream>>>(Wm, Wa, wmb, wab, batch, goff);

  // ---- DMPNN ----
  k_init_h8<<<(NN * 16 + 255) / 256, 256, 0, stream>>>(src, x, ea, Wi, hb);

  int ggrid = (NN + 63) / 64;
  for (int it = 0; it < 3; ++it) {  // depth = 3
    k_mfma<false><<<ggrid, 256, 0, stream>>>(hb, wmb, nullptr, nullptr, mb, NN);
    k_gather_x<<<8 * NBLK256, 256, 0, stream>>>(mb, rowptr, csr_src, hb);
  }

  k_node_agg3<<<(NN * 16 + 255) / 256, 256, 0, stream>>>(hb, rowptr, cur_lo,
                                                         csr_eid, zpk, Wi, mb);
  // node_act (into hb, tiled) = relu([x | ne] @ Wa.T)
  k_mfma<true><<<ggrid, 256, 0, stream>>>(mb, wab, x, Wa, hb, NN);

  k_pool<<<(NG * 16 + 255) / 256, 256, 0, stream>>>(hb, goff, g);

  dim3 grid1((NG + 63) / 64, 512 / 64);
  k_gemm64<true><<<grid1, 256, 0, stream>>>(g, W1, b1, g2, NG, 128, 512);
  dim3 grid2((NG + 63) / 64, 128 / 64);
  k_gemm64<false><<<grid2, 256, 0, stream>>>(g2, W2, b2, g3, NG, 512, 128);
  k_last<<<(NG * 64) / 256, 256, 0, stream>>>(g3, Wl, bl, out);
}

// Round 14
// 434.671 us; speedup vs baseline: 1.3181x; 1.3181x over previous
//
#include <hip/hip_runtime.h>

// DMPNN ChemModel — round 14: exact revert to round-12 best (436us).
// r13's nontemporal hints regressed (nt = L2-bypass on CDNA4: hT rmw stream
// went write-through to HBM, +15MB WRITE per gather, gathers 45->65us).
// Structure: XCD-pinned [8][NN][16] tiled bf16 storage; CSR lo-up/hi-down
// fill with packed hi-z; MFMA GEMMs (2x2 waves); node-major node_agg.
// Structural exploits:
//  - m[src] only reads rows < N_NODES -> per-depth GEMM is [N,128]@[128,128]
//  - scatter only updates rows < N_NODES -> store h[0:N]; rows >= N
//    recomputed from packed z (bf16) in node aggregation.
// depth hardcoded to 3.

#define NN 100000
#define NE 500000
#define HID 128
#define NG 2048
#define NB_SCAN 391    // ceil(NN/256)
#define NBLK256 391    // ceil(NN/256): per-plane blocks (256 nodes/block)

typedef __attribute__((ext_vector_type(8))) short bf16x8;
typedef __attribute__((ext_vector_type(4))) float f32x4;

__device__ __forceinline__ float b2f(ushort u) {
  return __uint_as_float(((uint)u) << 16);
}
__device__ __forceinline__ ushort f2b(float f) {
  uint u = __float_as_uint(f);
  return (ushort)((u + 0x7FFF + ((u >> 16) & 1)) >> 16);
}
__device__ __forceinline__ void acc8(float* a, bf16x8 v) {
#pragma unroll
  for (int j = 0; j < 8; ++j) a[j] += b2f((ushort)v[j]);
}
__device__ __forceinline__ bf16x8 pack8(const float* a) {
  bf16x8 o;
#pragma unroll
  for (int j = 0; j < 8; ++j) o[j] = (short)f2b(a[j]);
  return o;
}
// tiled address of the 16B chunk at (row n, col c8), c8 multiple of 8
__device__ __forceinline__ size_t taddr(int n, int c8) {
  return ((size_t)(c8 >> 4) * NN + n) * 16 + (c8 & 8);
}

// ------- K1: hT[e] = relu(W_i @ [x[src[e]], ea[e]]), 8 cols/thread ----------
__global__ __launch_bounds__(256) void k_init_h8(const int* __restrict__ src,
    const float* __restrict__ x, const float* __restrict__ ea,
    const float* __restrict__ Wi, ushort* __restrict__ hT) {
  __shared__ float wis[HID * 7];
  for (int i = threadIdx.x; i < HID * 7; i += 256) wis[i] = Wi[i];
  __syncthreads();
  int idx = blockIdx.x * 256 + threadIdx.x;
  int e = idx >> 4, chunk = idx & 15;
  if (e >= NN) return;
  int s = src[e];
  float4 xv = *reinterpret_cast<const float4*>(&x[(size_t)s * 4]);
  float e0 = ea[(size_t)e*3+0], e1 = ea[(size_t)e*3+1], e2 = ea[(size_t)e*3+2];
  const float* w = &wis[chunk * 56];
  float a[8];
#pragma unroll
  for (int j = 0; j < 8; ++j) {
    const float* wj = &w[j * 7];
    float t = xv.x*wj[0] + xv.y*wj[1] + xv.z*wj[2] + xv.w*wj[3]
            + e0*wj[4] + e1*wj[5] + e2*wj[6];
    a[j] = fmaxf(t, 0.f);
  }
  *reinterpret_cast<bf16x8*>(&hT[((size_t)(chunk >> 1) * NN + e) * 16 + (chunk & 1) * 8]) = pack8(a);
}

// ---------------- CSR build over dst ----------------------------------------
__global__ __launch_bounds__(256) void k_hist(const int* __restrict__ dst,
    int* __restrict__ cnt) {
  int e = blockIdx.x * 256 + threadIdx.x;
  if (e < NE) atomicAdd(&cnt[dst[e]], 1);
}

__global__ __launch_bounds__(256) void k_scan1(const int* __restrict__ cnt,
    int* __restrict__ outp, int* __restrict__ bsums) {
  __shared__ int s[256];
  int t = threadIdx.x;
  int i = blockIdx.x * 256 + t;
  int v = (i < NN) ? cnt[i] : 0;
  s[t] = v;
  __syncthreads();
  for (int off = 1; off < 256; off <<= 1) {
    int u = (t >= off) ? s[t - off] : 0;
    __syncthreads();
    s[t] += u;
    __syncthreads();
  }
  if (i < NN) outp[i] = s[t] - v;
  if (t == 255) bsums[blockIdx.x] = s[255];
}

__global__ __launch_bounds__(512) void k_scan2(int* __restrict__ bsums) {
  __shared__ int s[512];
  int t = threadIdx.x;
  int v = (t < NB_SCAN) ? bsums[t] : 0;
  s[t] = v;
  __syncthreads();
  for (int off = 1; off < 512; off <<= 1) {
    int u = (t >= off) ? s[t - off] : 0;
    __syncthreads();
    s[t] += u;
    __syncthreads();
  }
  if (t < NB_SCAN) bsums[t] = s[t] - v;
}

__global__ __launch_bounds__(256) void k_scan3(int* __restrict__ outp,
    const int* __restrict__ bsums) {
  int i = blockIdx.x * 256 + threadIdx.x;
  if (i < NN) outp[i] += bsums[blockIdx.x];
  if (i == 0) outp[NN] = NE;
}

// fill CSR: lo edges (e<NN) fill UP from rowptr[d] (csr_eid recorded);
// hi edges fill DOWN from rowptr[d+1]-1 with packed z. After this kernel,
// cur_lo[d] == lo-count of d (node_agg uses mid = rowptr[d] + cur_lo[d]).
__global__ __launch_bounds__(256) void k_fill2z(const int* __restrict__ src,
    const int* __restrict__ dst, const int* __restrict__ rowptr,
    int* __restrict__ cur_lo, int* __restrict__ cur_hi,
    int* __restrict__ csr_src, int* __restrict__ csr_eid,
    const float* __restrict__ x, const float* __restrict__ ea,
    ushort* __restrict__ zpk) {
  int e = blockIdx.x * 256 + threadIdx.x;
  if (e >= NE) return;
  int d = dst[e];
  int s = src[e];
  int o;
  if (e < NN) {
    o = rowptr[d] + atomicAdd(&cur_lo[d], 1);
    csr_eid[o] = e;
  } else {
    o = rowptr[d + 1] - 1 - atomicAdd(&cur_hi[d], 1);
    float4 xv = *reinterpret_cast<const float4*>(&x[(size_t)s * 4]);
    bf16x8 z;
    z[0] = (short)f2b(xv.x); z[1] = (short)f2b(xv.y);
    z[2] = (short)f2b(xv.z); z[3] = (short)f2b(xv.w);
    z[4] = (short)f2b(ea[(size_t)e*3+0]);
    z[5] = (short)f2b(ea[(size_t)e*3+1]);
    z[6] = (short)f2b(ea[(size_t)e*3+2]);
    z[7] = 0;
    *reinterpret_cast<bf16x8*>(&zpk[(size_t)o * 8]) = z;
  }
  csr_src[o] = s;
}

// weight convert (blocks 0..63) + graph offsets (blocks 64..72), fused
__global__ __launch_bounds__(256) void k_misc(const float* __restrict__ Wm,
    const float* __restrict__ Wa, ushort* __restrict__ wmb,
    ushort* __restrict__ wab, const int* __restrict__ batch,
    int* __restrict__ goff) {
  int gb = blockIdx.x;
  if (gb < 64) {
    int i = gb * 256 + threadIdx.x;
    wmb[i] = f2b(Wm[i]);
    int c = i >> 7, k = i & 127;
    wab[i] = f2b(Wa[c * 132 + 4 + k]);
  } else {
    int g = (gb - 64) * 256 + threadIdx.x;
    if (g > NG) return;
    int lo = 0, hi = NN;
    while (lo < hi) { int mid = (lo + hi) >> 1; if (batch[mid] < g) lo = mid + 1; else hi = mid; }
    goff[g] = lo;
  }
}

// ---- MFMA GEMM (2x2 waves, tiled A/O): O = relu(A@Wb.T [+x-part]) ----------
template <bool HASX>
__global__ __launch_bounds__(256) void k_mfma(const ushort* __restrict__ A,
    const ushort* __restrict__ Wb, const float* __restrict__ X,
    const float* __restrict__ WaF, ushort* __restrict__ O, int nrows) {
  int tid = threadIdx.x;
  int wave = tid >> 6;
  int lane = tid & 63;
  int wr = wave >> 1, wc = wave & 1;
  int row0 = blockIdx.x * 64 + wr * 32;
  int col0 = wc * 64;
  int l15 = lane & 15, l4 = lane >> 4;

  f32x4 acc[2][4];
#pragma unroll
  for (int mi = 0; mi < 2; ++mi)
#pragma unroll
    for (int ni = 0; ni < 4; ++ni) acc[mi][ni] = (f32x4){0.f, 0.f, 0.f, 0.f};

  if (HASX) {
    float4 wv[4];
#pragma unroll
    for (int ni = 0; ni < 4; ++ni)
      wv[ni] = *reinterpret_cast<const float4*>(&WaF[(size_t)(col0 + ni * 16 + l15) * 132]);
#pragma unroll
    for (int mi = 0; mi < 2; ++mi)
#pragma unroll
      for (int j = 0; j < 4; ++j) {
        int r = row0 + mi * 16 + l4 * 4 + j;
        if (r < nrows) {
          float4 xv = *reinterpret_cast<const float4*>(&X[(size_t)r * 4]);
#pragma unroll
          for (int ni = 0; ni < 4; ++ni)
            acc[mi][ni][j] = xv.x * wv[ni].x + xv.y * wv[ni].y
                           + xv.z * wv[ni].z + xv.w * wv[ni].w;
        }
      }
  }

  const bf16x8 zero8 = {0, 0, 0, 0, 0, 0, 0, 0};
#pragma unroll
  for (int k0 = 0; k0 < HID; k0 += 32) {
    bf16x8 a[2], b[4];
    int c8 = k0 + l4 * 8;
#pragma unroll
    for (int mi = 0; mi < 2; ++mi) {
      int r = row0 + mi * 16 + l15;
      a[mi] = (r < nrows)
            ? *reinterpret_cast<const bf16x8*>(&A[taddr(r, c8)])
            : zero8;
    }
#pragma unroll
    for (int ni = 0; ni < 4; ++ni) {
      int c = col0 + ni * 16 + l15;
      b[ni] = *reinterpret_cast<const bf16x8*>(&Wb[(size_t)c * HID + k0 + l4 * 8]);
    }
#pragma unroll
    for (int mi = 0; mi < 2; ++mi)
#pragma unroll
      for (int ni = 0; ni < 4; ++ni)
        acc[mi][ni] = __builtin_amdgcn_mfma_f32_16x16x32_bf16(a[mi], b[ni], acc[mi][ni], 0, 0, 0);
  }

#pragma unroll
  for (int mi = 0; mi < 2; ++mi)
#pragma unroll
    for (int j = 0; j < 4; ++j) {
      int r = row0 + mi * 16 + l4 * 4 + j;
      if (r >= nrows) continue;
#pragma unroll
      for (int ni = 0; ni < 4; ++ni) {
        int plane = wc * 4 + ni;  // (col0 + ni*16) >> 4
        O[((size_t)plane * NN + r) * 16 + l15] = f2b(fmaxf(acc[mi][ni][j], 0.f));
      }
    }
}

// ----- K3: XCD-pinned plane gather; 1 thread/(node,plane) owns 32B ----------
// plane = bid & 7 (round-robin dispatch pins plane p to XCD p; 3.2MB mT plane
// L2-resident). Sequential n -> coalesced h base rw. 4-wide exact-predicated
// edge batches x 2 halves = 8 loads in flight.
__global__ __launch_bounds__(256) void k_gather_x(const ushort* __restrict__ mT,
    const int* __restrict__ rowptr, const int* __restrict__ csr_src,
    ushort* __restrict__ hT) {
  int plane = blockIdx.x & 7;
  int nb = blockIdx.x >> 3;
  int n = nb * 256 + threadIdx.x;
  if (n >= NN) return;
  size_t pb = (size_t)plane * NN;
  size_t base = (pb + n) * 16;
  const bf16x8 zero8 = {0, 0, 0, 0, 0, 0, 0, 0};
  float a[16];
  bf16x8 h0 = *reinterpret_cast<const bf16x8*>(&hT[base]);
  bf16x8 h1 = *reinterpret_cast<const bf16x8*>(&hT[base + 8]);
#pragma unroll
  for (int j = 0; j < 8; ++j) { a[j] = b2f((ushort)h0[j]); a[8+j] = b2f((ushort)h1[j]); }
  int beg = rowptr[n], end = rowptr[n + 1];
  for (int i = beg; i < end; i += 4) {
    bf16x8 v0[4], v1[4];
#pragma unroll
    for (int k = 0; k < 4; ++k) {
      v0[k] = zero8; v1[k] = zero8;
      if (i + k < end) {
        size_t sb = (pb + csr_src[i + k]) * 16;
        v0[k] = *reinterpret_cast<const bf16x8*>(&mT[sb]);
        v1[k] = *reinterpret_cast<const bf16x8*>(&mT[sb + 8]);
      }
    }
#pragma unroll
    for (int k = 0; k < 4; ++k) { acc8(a, v0[k]); acc8(a + 8, v1[k]); }
  }
  *reinterpret_cast<bf16x8*>(&hT[base]) = pack8(a);
  *reinterpret_cast<bf16x8*>(&hT[base + 8]) = pack8(a + 8);
}

// ------ K4: node-major node_agg (16 t/node): zpk read ONCE ------------------
// mid = rowptr[n] + locnt[n] (locnt = cur_lo after fill).
__global__ __launch_bounds__(256) void k_node_agg3(const ushort* __restrict__ hT,
    const int* __restrict__ rowptr, const int* __restrict__ locnt,
    const int* __restrict__ csr_eid, const ushort* __restrict__ zpk,
    const float* __restrict__ Wi, ushort* __restrict__ neT) {
  int idx = blockIdx.x * 256 + threadIdx.x;
  int n = idx >> 4;
  int t = idx & 15;
  int plane = t >> 1;
  int half8 = (t & 1) * 8;
  int c8 = t * 8;
  float w[8][7];
#pragma unroll
  for (int j = 0; j < 8; ++j)
#pragma unroll
    for (int k = 0; k < 7; ++k) w[j][k] = Wi[(c8 + j) * 7 + k];
  if (n >= NN) return;
  size_t pb = (size_t)plane * NN;
  int beg = rowptr[n], end = rowptr[n + 1];
  int mid = beg + locnt[n];
  const bf16x8 zero8 = {0, 0, 0, 0, 0, 0, 0, 0};
  float a[8];
#pragma unroll
  for (int j = 0; j < 8; ++j) a[j] = 0.f;

  // lo: e < NN -> hT rows, exact predicated 4-batches
  for (int i = beg; i < mid; i += 4) {
    bf16x8 v[4];
#pragma unroll
    for (int k = 0; k < 4; ++k) {
      v[k] = zero8;
      if (i + k < mid) {
        int e = csr_eid[i + k];
        v[k] = *reinterpret_cast<const bf16x8*>(&hT[(pb + e) * 16 + half8]);
      }
    }
#pragma unroll
    for (int k = 0; k < 4; ++k) acc8(a, v[k]);
  }

  // hi: packed z, 16 lanes of a node share each 16B read (1 request)
  for (int i = mid; i < end; i += 4) {
    bf16x8 zv[4];
#pragma unroll
    for (int k = 0; k < 4; ++k) {
      zv[k] = zero8;
      if (i + k < end)
        zv[k] = *reinterpret_cast<const bf16x8*>(&zpk[(size_t)(i + k) * 8]);
    }
#pragma unroll
    for (int k = 0; k < 4; ++k) {
      if (i + k < end) {
        float z0 = b2f((ushort)zv[k][0]), z1 = b2f((ushort)zv[k][1]);
        float z2 = b2f((ushort)zv[k][2]), z3 = b2f((ushort)zv[k][3]);
        float z4 = b2f((ushort)zv[k][4]), z5 = b2f((ushort)zv[k][5]);
        float z6 = b2f((ushort)zv[k][6]);
#pragma unroll
        for (int j = 0; j < 8; ++j) {
          float tt = z0*w[j][0] + z1*w[j][1] + z2*w[j][2] + z3*w[j][3]
                   + z4*w[j][4] + z5*w[j][5] + z6*w[j][6];
          a[j] += fmaxf(tt, 0.f);
        }
      }
    }
  }
  *reinterpret_cast<bf16x8*>(&neT[(pb + n) * 16 + half8]) = pack8(a);
}

// ---------------- K6: g[gid] = sum of tiled node_act rows (fp32 out) --------
__global__ __launch_bounds__(256) void k_pool(const ushort* __restrict__ na,
    const int* __restrict__ goff, float* __restrict__ g) {
  int idx = blockIdx.x * 256 + threadIdx.x;
  int gid = idx >> 4;
  if (gid >= NG) return;
  int c8 = (idx & 15) * 8;
  size_t pbase = (size_t)(c8 >> 4) * NN;
  int off = c8 & 8;
  int beg = goff[gid], end = goff[gid + 1];
  float a[8];
#pragma unroll
  for (int j = 0; j < 8; ++j) a[j] = 0.f;
  for (int n = beg; n < end; ++n)
    acc8(a, *reinterpret_cast<const bf16x8*>(&na[(pbase + n) * 16 + off]));
  *reinterpret_cast<float4*>(&g[(size_t)gid * HID + c8]) = make_float4(a[0], a[1], a[2], a[3]);
  *reinterpret_cast<float4*>(&g[(size_t)gid * HID + c8 + 4]) = make_float4(a[4], a[5], a[6], a[7]);
}

// ---------------- FFN fp32 GEMM + final dot ---------------------------------
template <bool RELU>
__global__ __launch_bounds__(256) void k_gemm64(const float* __restrict__ A,
    const float* __restrict__ W, const float* __restrict__ bias,
    float* __restrict__ O, int nrows, int K, int N) {
  __shared__ float As[64][33];
  __shared__ float Bs[32][68];
  int tid = threadIdx.x;
  int row0 = blockIdx.x * 64;
  int col0 = blockIdx.y * 64;
  int tn = tid & 15;
  int tm = tid >> 4;
  float acc[4][4];
#pragma unroll
  for (int i = 0; i < 4; ++i)
#pragma unroll
    for (int j = 0; j < 4; ++j) acc[i][j] = 0.f;

  for (int k0 = 0; k0 < K; k0 += 32) {
    int ar = tid >> 3;
    int ak = (tid & 7) << 2;
#pragma unroll
    for (int rr = 0; rr < 2; ++rr) {
      int r = row0 + ar + rr * 32;
      float4 v = make_float4(0.f, 0.f, 0.f, 0.f);
      if (r < nrows) v = *reinterpret_cast<const float4*>(&A[(size_t)r * K + k0 + ak]);
      As[ar + rr*32][ak+0] = v.x; As[ar + rr*32][ak+1] = v.y;
      As[ar + rr*32][ak+2] = v.z; As[ar + rr*32][ak+3] = v.w;
    }
    int c = tid & 63;
    int kq = tid >> 6;
#pragma unroll
    for (int it = 0; it < 2; ++it) {
      int kk = kq * 4 + it * 16;
      float4 v = *reinterpret_cast<const float4*>(&W[(size_t)(col0 + c) * K + k0 + kk]);
      Bs[kk+0][c] = v.x; Bs[kk+1][c] = v.y; Bs[kk+2][c] = v.z; Bs[kk+3][c] = v.w;
    }
    __syncthreads();
#pragma unroll 8
    for (int k = 0; k < 32; ++k) {
      float av[4];
#pragma unroll
      for (int i = 0; i < 4; ++i) av[i] = As[tm*4 + i][k];
      float4 bv = *reinterpret_cast<const float4*>(&Bs[k][tn*4]);
#pragma unroll
      for (int i = 0; i < 4; ++i) {
        acc[i][0] = fmaf(av[i], bv.x, acc[i][0]);
        acc[i][1] = fmaf(av[i], bv.y, acc[i][1]);
        acc[i][2] = fmaf(av[i], bv.z, acc[i][2]);
        acc[i][3] = fmaf(av[i], bv.w, acc[i][3]);
      }
    }
    __syncthreads();
  }
#pragma unroll
  for (int i = 0; i < 4; ++i) {
    int r = row0 + tm * 4 + i;
    if (r >= nrows) continue;
    float4 o;
    int c = col0 + tn * 4;
    o.x = acc[i][0] + bias[c+0];
    o.y = acc[i][1] + bias[c+1];
    o.z = acc[i][2] + bias[c+2];
    o.w = acc[i][3] + bias[c+3];
    if (RELU) {
      o.x = fmaxf(o.x, 0.f); o.y = fmaxf(o.y, 0.f);
      o.z = fmaxf(o.z, 0.f); o.w = fmaxf(o.w, 0.f);
    }
    *reinterpret_cast<float4*>(&O[(size_t)r * N + c]) = o;
  }
}

__global__ __launch_bounds__(256) void k_last(const float* __restrict__ g3,
    const float* __restrict__ Wl, const float* __restrict__ bl,
    float* __restrict__ out) {
  int wid = (blockIdx.x * 256 + threadIdx.x) >> 6;
  int lane = threadIdx.x & 63;
  if (wid >= NG) return;
  float a = g3[(size_t)wid*128 + lane] * Wl[lane]
          + g3[(size_t)wid*128 + 64 + lane] * Wl[64 + lane];
  for (int off = 32; off; off >>= 1) a += __shfl_down(a, off);
  if (lane == 0) out[wid] = a + bl[0];
}

extern "C" void kernel_launch(void* const* d_in, const int* in_sizes, int n_in,
                              void* d_out, int out_size, void* d_ws, size_t ws_size,
                              hipStream_t stream) {
  const float* x    = (const float*)d_in[0];
  const int*   eidx = (const int*)d_in[1];
  const float* ea   = (const float*)d_in[2];
  const int*   batch= (const int*)d_in[3];
  const float* Wi   = (const float*)d_in[5];
  const float* Wm   = (const float*)d_in[6];
  const float* Wa   = (const float*)d_in[7];
  const float* W1   = (const float*)d_in[8];
  const float* b1   = (const float*)d_in[9];
  const float* W2   = (const float*)d_in[10];
  const float* b2   = (const float*)d_in[11];
  const float* Wl   = (const float*)d_in[12];
  const float* bl   = (const float*)d_in[13];
  float* out = (float*)d_out;

  const int* src = eidx;
  const int* dst = eidx + NE;

  // ---- workspace layout ----
  char* p = (char*)d_ws;
  ushort* hb  = (ushort*)p; p += (size_t)NN * HID * 2;   // 25.6 MB (tiled [8][NN][16])
  ushort* mb  = (ushort*)p; p += (size_t)NN * HID * 2;   // 25.6 MB (tiled)
  ushort* wmb = (ushort*)p; p += (size_t)HID * HID * 2;  // 32 KB
  ushort* wab = (ushort*)p; p += (size_t)HID * HID * 2;  // 32 KB
  ushort* zpk = (ushort*)p; p += (size_t)NE * 8 * 2;     // 8 MB (bf16x8 per CSR slot)
  float* g  = (float*)p; p += (size_t)NG * 128 * 4;      // 1 MB
  float* g2 = (float*)p; p += (size_t)NG * 512 * 4;      // 4 MB
  float* g3 = (float*)p; p += (size_t)NG * 128 * 4;      // 1 MB
  int* csr_src = (int*)p; p += (size_t)NE * 4;           // 2 MB
  int* csr_eid = (int*)p; p += (size_t)NE * 4;           // 2 MB
  // zeroed region: cnt | cur_lo | cur_hi  (3*NN ints)
  int* cnt    = (int*)p; p += (size_t)NN * 4;
  int* cur_lo = (int*)p; p += (size_t)NN * 4;
  int* cur_hi = (int*)p; p += (size_t)NN * 4;
  // un-zeroed
  int* rowptr = (int*)p; p += (size_t)(NN + 4) * 4;
  int* bsums  = (int*)p; p += 512 * 4;
  int* goff   = (int*)p; p += (size_t)(NG + 4) * 4;

  // ---- CSR over dst (lo up-fill / hi down-fill) + hi-z + goff ----
  hipMemsetAsync(cnt, 0, (size_t)3 * NN * sizeof(int), stream);
  k_hist <<<(NE + 255) / 256, 256, 0, stream>>>(dst, cnt);
  k_scan1<<<NB_SCAN, 256, 0, stream>>>(cnt, rowptr, bsums);
  k_scan2<<<1, 512, 0, stream>>>(bsums);
  k_scan3<<<NB_SCAN, 256, 0, stream>>>(rowptr, bsums);
  k_fill2z<<<(NE + 255) / 256, 256, 0, stream>>>(src, dst, rowptr,
                                                 cur_lo, cur_hi, csr_src, csr_eid,
                                                 x, ea, zpk);
  k_misc<<<64 + 9, 256, 0, stream>>>(Wm, Wa, wmb, wab, batch, goff);

  // ---- DMPNN ----
  k_init_h8<<<(NN * 16 + 255) / 256, 256, 0, stream>>>(src, x, ea, Wi, hb);

  int ggrid = (NN + 63) / 64;
  for (int it = 0; it < 3; ++it) {  // depth = 3
    k_mfma<false><<<ggrid, 256, 0, stream>>>(hb, wmb, nullptr, nullptr, mb, NN);
    k_gather_x<<<8 * NBLK256, 256, 0, stream>>>(mb, rowptr, csr_src, hb);
  }

  k_node_agg3<<<(NN * 16 + 255) / 256, 256, 0, stream>>>(hb, rowptr, cur_lo,
                                                         csr_eid, zpk, Wi, mb);
  // node_act (into hb, tiled) = relu([x | ne] @ Wa.T)
  k_mfma<true><<<ggrid, 256, 0, stream>>>(mb, wab, x, Wa, hb, NN);

  k_pool<<<(NG * 16 + 255) / 256, 256, 0, stream>>>(hb, goff, g);

  dim3 grid1((NG + 63) / 64, 512 / 64);
  k_gemm64<true><<<grid1, 256, 0, stream>>>(g, W1, b1, g2, NG, 128, 512);
  dim3 grid2((NG + 63) / 64, 128 / 64);
  k_gemm64<false><<<grid2, 256, 0, stream>>>(g2, W2, b2, g3, NG, 512, 128);
  k_last<<<(NG * 64) / 256, 256, 0, stream>>>(g3, Wl, bl, out);
}